// Round 1
// baseline (1854.594 us; speedup 1.0000x reference)
//
#include <hip/hip_runtime.h>
#include <hip/hip_bf16.h>
#include <math.h>

#define Tn 1024
#define Cn 960
#define Hn 15
#define Nn 64
#define Mn 4096  // B*T

__device__ __forceinline__ float sigmf(float x) { return 1.0f / (1.0f + __expf(-x)); }

__device__ __forceinline__ void bar() {
    // producer-side: ensure our LDS writes/reads retired, then barrier.
    // Deliberately does NOT drain vmcnt so global prefetch stays in flight.
    asm volatile("s_waitcnt lgkmcnt(0)" ::: "memory");
    __builtin_amdgcn_s_barrier();
}

// ---------------------------------------------------------------------------
// token-shift + 6 mixes: out_j = x + (shift(x) - x) * mix_j
// ---------------------------------------------------------------------------
__global__ __launch_bounds__(256) void mix6_kernel(
    const float* __restrict__ x,
    const float* __restrict__ mr, const float* __restrict__ mw, const float* __restrict__ mk,
    const float* __restrict__ mv, const float* __restrict__ ma, const float* __restrict__ mg,
    float* __restrict__ o_r, float* __restrict__ o_w, float* __restrict__ o_k,
    float* __restrict__ o_v, float* __restrict__ o_a, float* __restrict__ o_g)
{
    int idx = blockIdx.x * 256 + threadIdx.x;  // float4 index
    int e = idx * 4;
    if (e >= Mn * Cn) return;
    int m = e / Cn;
    int c = e - m * Cn;
    int t = m & (Tn - 1);
    float4 xv = *(const float4*)(x + e);
    float4 xp = make_float4(0.f, 0.f, 0.f, 0.f);
    if (t > 0) xp = *(const float4*)(x + e - Cn);
    float4 dx = make_float4(xp.x - xv.x, xp.y - xv.y, xp.z - xv.z, xp.w - xv.w);
#define APPLY(MIXP, OUTP)                                                     \
    {                                                                         \
        float4 mm = *(const float4*)(MIXP + c);                               \
        float4 o = make_float4(xv.x + dx.x * mm.x, xv.y + dx.y * mm.y,        \
                               xv.z + dx.z * mm.z, xv.w + dx.w * mm.w);       \
        *(float4*)(OUTP + e) = o;                                             \
    }
    APPLY(mr, o_r) APPLY(mw, o_w) APPLY(mk, o_k)
    APPLY(mv, o_v) APPLY(ma, o_a) APPLY(mg, o_g)
#undef APPLY
}

// ---------------------------------------------------------------------------
// plain f32 GEMM: C[M,N] = A[M,K] @ B[K,N].  M from grid (64/row-tile).
// BM=64 BN=64 BK=16, 256 threads, 4x4 per thread. N,K need not be mult of 64
// (N mult of 32, K mult of 16).
// ---------------------------------------------------------------------------
__global__ __launch_bounds__(256) void gemm64_kernel(
    const float* __restrict__ A, int lda,
    const float* __restrict__ Bw, int ldb,
    float* __restrict__ Cc, int ldc, int N, int K)
{
    __shared__ float As[16][68];  // transposed, padded stride 68 (16B aligned, spreads banks)
    __shared__ float Bs[16][64];
    int bm = blockIdx.x * 64, bn = blockIdx.y * 64;
    int tid = threadIdx.x;
    int tx = tid & 15, ty = tid >> 4;
    int ar = tid >> 2, ak = (tid & 3) * 4;
    int bkr = tid >> 4, bnc = (tid & 15) * 4;
    bool bok = (bn + bnc) < N;
    const float* Aptr = A + (size_t)(bm + ar) * lda + ak;
    const float* Bptr = Bw + (size_t)bkr * ldb + bn + bnc;
    float acc[4][4];
#pragma unroll
    for (int i = 0; i < 4; ++i)
#pragma unroll
        for (int j = 0; j < 4; ++j) acc[i][j] = 0.f;

    for (int k0 = 0; k0 < K; k0 += 16) {
        float4 a4 = *(const float4*)(Aptr + k0);
        float4 b4 = make_float4(0.f, 0.f, 0.f, 0.f);
        if (bok) b4 = *(const float4*)(Bptr + (size_t)k0 * ldb);
        As[ak + 0][ar] = a4.x;
        As[ak + 1][ar] = a4.y;
        As[ak + 2][ar] = a4.z;
        As[ak + 3][ar] = a4.w;
        *(float4*)&Bs[bkr][bnc] = b4;
        __syncthreads();
#pragma unroll
        for (int kk = 0; kk < 16; ++kk) {
            float4 av = *(const float4*)&As[kk][ty * 4];
            float4 bv = *(const float4*)&Bs[kk][tx * 4];
            float aa[4] = {av.x, av.y, av.z, av.w};
            float bb[4] = {bv.x, bv.y, bv.z, bv.w};
#pragma unroll
            for (int i = 0; i < 4; ++i)
#pragma unroll
                for (int j = 0; j < 4; ++j) acc[i][j] += aa[i] * bb[j];
        }
        __syncthreads();
    }
    if (bok) {
#pragma unroll
        for (int i = 0; i < 4; ++i) {
            int row = bm + ty * 4 + i;
            float4 st = make_float4(acc[i][0], acc[i][1], acc[i][2], acc[i][3]);
            *(float4*)(Cc + (size_t)row * ldc + bn + tx * 4) = st;
        }
    }
}

// ---------------------------------------------------------------------------
// activations on hid: cols [0,64) tanh (w), [64,128) none (a), [128,160) none
// (v), [160,288) sigmoid (g)
// ---------------------------------------------------------------------------
__global__ __launch_bounds__(256) void hidact_kernel(float* hid)
{
    int idx = blockIdx.x * 256 + threadIdx.x;
    if (idx >= Mn * 288) return;
    int c = idx % 288;
    float v = hid[idx];
    if (c < 64) v = tanhf(v);
    else if (c >= 160) v = sigmf(v);
    hid[idx] = v;
}

// ---------------------------------------------------------------------------
// elementwise stage 3: w, a, v-residual, kk-norm, kh, ah, bh.
// one wave per (m, h); 4 pairs per block. NOTE: out ptrs alias in ptrs
// (per-element in-place) so no __restrict__ here.
// ---------------------------------------------------------------------------
__global__ __launch_bounds__(256) void stage3e_kernel(
    const float* wrawp, const float* aprep, const float* vsigp,
    const float* kraw, const float* vfirst,
    const float* w0, const float* a0, const float* v0c,
    const float* kkc, const float* kac,
    float* w_out, float* v_io, float* ah_out, float* bh_out, float* kh_out)
{
    int p = blockIdx.x * 4 + (threadIdx.x >> 6);
    int l = threadIdx.x & 63;
    int m = p / Hn;
    int h = p - m * Hn;
    int c = h * 64 + l;
    size_t idx = (size_t)m * Cn + c;
    float k = kraw[idx];
    float wr = w0[c] + wrawp[idx];
    float a = sigmf(a0[c] + aprep[idx]);
    float vs = sigmf(v0c[c] + vsigp[idx]);
    float v0g = v_io[idx];
    float v = v0g + (vfirst[idx] - v0g) * vs;
    float kk = k * kkc[c];
    float ss = kk * kk;
#pragma unroll
    for (int o = 32; o; o >>= 1) ss += __shfl_xor(ss, o);
    float inv = 1.0f / fmaxf(sqrtf(ss), 1e-12f);
    kk *= inv;
    float w = sigmf(wr) * 0.60653065971263342f;  // sigmoid(wr)*exp(-0.5)
    float kh = k * (1.0f + (a - 1.0f) * kac[c]);
    w_out[idx] = w;
    v_io[idx] = v;
    ah_out[idx] = -kk;
    bh_out[idx] = kk * a;
    kh_out[idx] = kk * a * 0.f + kh;  // keep order obvious; kh computed from pre-read k,a
}

// ---------------------------------------------------------------------------
// sequential WKV scan, fused groupnorm + bonus + gate.
// grid = B*H blocks, 256 threads (4 waves). thread (q=tid>>6, i=tid&63)
// owns state row i, cols [16q,16q+16). Raw barriers keep prefetch in flight.
// ---------------------------------------------------------------------------
__global__ __launch_bounds__(256) void scan_kernel(
    const float* __restrict__ rP, const float* __restrict__ wP,
    const float* __restrict__ kP, const float* __restrict__ aP,
    const float* __restrict__ bP, const float* __restrict__ vP,
    const float* __restrict__ gP, const float* __restrict__ r_k,
    const float* __restrict__ ln_g, const float* __restrict__ ln_b,
    float* __restrict__ xog)
{
    __shared__ float vecs[7 * 64];     // r,w,k,a,b,v,g
    __shared__ float sap[4][64];
    __shared__ float outp[4][64];
    int tid = threadIdx.x;
    int q = tid >> 6, i = tid & 63;
    int bh = blockIdx.x;
    int bb = bh / Hn, h = bh - bb * Hn;
    size_t base = (size_t)bb * Tn * Cn + h * 64;

    const float* P0[4] = {rP, wP, kP, aP};
    const float* P1[3] = {bP, vP, gP};
    const float* myA = P0[q] + base + i;
    const float* myB = (q < 3) ? (P1[q] + base + i) : (P0[0] + base + i);
    bool hasB = (q < 3);

    float s[16];
#pragma unroll
    for (int z = 0; z < 16; ++z) s[z] = 0.f;
    float rk = r_k[h * 64 + i];
    float lng = ln_g[h * 64 + i];
    float lnb = ln_b[h * 64 + i];

    float pa = *myA;
    float pb = *myB;
    float* orow = xog + base + i;

    for (int t = 0; t < Tn; ++t) {
        bar();  // protect LDS overwrite vs previous iteration's readers
        vecs[q * 64 + i] = pa;
        if (hasB) vecs[(4 + q) * 64 + i] = pb;
        bar();  // data visible
        // prefetch t+1 (stays in flight across raw barriers)
        int adv = (t < Tn - 1) ? Cn : 0;
        myA += adv;
        myB += adv;
        pa = *myA;
        pb = *myB;

        // sa partial over own 16 columns
        const float* av = &vecs[3 * 64 + q * 16];
        float sp = 0.f;
#pragma unroll
        for (int z = 0; z < 16; z += 4) {
            float4 a4 = *(const float4*)(av + z);
            sp += s[z] * a4.x + s[z + 1] * a4.y + s[z + 2] * a4.z + s[z + 3] * a4.w;
        }
        sap[q][i] = sp;
        bar();
        float sa = sap[0][i] + sap[1][i] + sap[2][i] + sap[3][i];
        float vi = vecs[5 * 64 + i];
        const float* wv = &vecs[1 * 64 + q * 16];
        const float* kv = &vecs[2 * 64 + q * 16];
        const float* bv = &vecs[4 * 64 + q * 16];
        const float* rv = &vecs[0 * 64 + q * 16];
        float op = 0.f;
#pragma unroll
        for (int z = 0; z < 16; z += 4) {
            float4 w4 = *(const float4*)(wv + z);
            float4 k4 = *(const float4*)(kv + z);
            float4 b4 = *(const float4*)(bv + z);
            float4 r4 = *(const float4*)(rv + z);
            s[z + 0] = s[z + 0] * w4.x + sa * b4.x + vi * k4.x; op += s[z + 0] * r4.x;
            s[z + 1] = s[z + 1] * w4.y + sa * b4.y + vi * k4.y; op += s[z + 1] * r4.y;
            s[z + 2] = s[z + 2] * w4.z + sa * b4.z + vi * k4.z; op += s[z + 2] * r4.z;
            s[z + 3] = s[z + 3] * w4.w + sa * b4.w + vi * k4.w; op += s[z + 3] * r4.w;
        }
        outp[q][i] = op;
        bar();
        if (q == 0) {
            float out = outp[0][i] + outp[1][i] + outp[2][i] + outp[3][i];
            float m1 = out, m2 = out * out;
            float bd = vecs[0 * 64 + i] * vecs[2 * 64 + i] * rk;  // r*kh*r_k
#pragma unroll
            for (int o = 32; o; o >>= 1) {
                m1 += __shfl_xor(m1, o);
                m2 += __shfl_xor(m2, o);
                bd += __shfl_xor(bd, o);
            }
            float mean = m1 * (1.f / 64.f);
            float var = m2 * (1.f / 64.f) - mean * mean;
            float xn = (out - mean) * rsqrtf(var + 0.00064f) * lng + lnb;
            float bonus = bd * vecs[5 * 64 + i];
            float gv = vecs[6 * 64 + i];
            orow[0] = (xn + bonus) * gv;
        }
        orow += Cn;
    }
}

// ---------------------------------------------------------------------------
extern "C" void kernel_launch(void* const* d_in, const int* in_sizes, int n_in,
                              void* d_out, int out_size, void* d_ws, size_t ws_size,
                              hipStream_t stream)
{
    const float* x       = (const float*)d_in[0];
    const float* v_first = (const float*)d_in[1];
    const float* x_r     = (const float*)d_in[2];
    const float* x_w     = (const float*)d_in[3];
    const float* x_k     = (const float*)d_in[4];
    const float* x_v     = (const float*)d_in[5];
    const float* x_a     = (const float*)d_in[6];
    const float* x_g     = (const float*)d_in[7];
    const float* w0      = (const float*)d_in[8];
    const float* w1      = (const float*)d_in[9];
    const float* w2      = (const float*)d_in[10];
    const float* a0      = (const float*)d_in[11];
    const float* a1      = (const float*)d_in[12];
    const float* a2      = (const float*)d_in[13];
    const float* v0c     = (const float*)d_in[14];
    const float* v1      = (const float*)d_in[15];
    const float* v2      = (const float*)d_in[16];
    const float* g1w     = (const float*)d_in[17];
    const float* g2w     = (const float*)d_in[18];
    const float* k_k     = (const float*)d_in[19];
    const float* k_a     = (const float*)d_in[20];
    const float* r_k     = (const float*)d_in[21];
    const float* Wr      = (const float*)d_in[22];
    const float* Wk      = (const float*)d_in[23];
    const float* Wv      = (const float*)d_in[24];
    const float* Wo      = (const float*)d_in[25];
    const float* ln_g    = (const float*)d_in[26];
    const float* ln_b    = (const float*)d_in[27];
    float* out = (float*)d_out;

    float* ws = (float*)d_ws;
    size_t MC = (size_t)Mn * Cn;
    float* B0 = ws + 0 * MC;  // xr -> wraw -> ah
    float* B1 = ws + 1 * MC;  // xw -> w
    float* B2 = ws + 2 * MC;  // xk -> apre -> bh
    float* B3 = ws + 3 * MC;  // xv -> vsigp -> kh
    float* B4 = ws + 4 * MC;  // xa -> xog
    float* B5 = ws + 5 * MC;  // xg -> g
    float* B6 = ws + 6 * MC;  // r
    float* B7 = ws + 7 * MC;  // k (raw)
    float* B8 = ws + 8 * MC;  // v0 -> v
    float* hid = ws + 9 * MC; // [Mn,288]

    mix6_kernel<<<3840, 256, 0, stream>>>(x, x_r, x_w, x_k, x_v, x_a, x_g,
                                          B0, B1, B2, B3, B4, B5);

    dim3 gBig(64, 15);
    // stage 1: big projections
    gemm64_kernel<<<gBig, 256, 0, stream>>>(B0, Cn, Wr, Cn, B6, Cn, Cn, Cn);
    gemm64_kernel<<<gBig, 256, 0, stream>>>(B2, Cn, Wk, Cn, B7, Cn, Cn, Cn);
    gemm64_kernel<<<gBig, 256, 0, stream>>>(B3, Cn, Wv, Cn, B8, Cn, Cn, Cn);
    // stage 2: lora-down GEMMs into hid
    dim3 g64(64, 1);
    gemm64_kernel<<<g64, 256, 0, stream>>>(B1, Cn, w1, 64, hid + 0, 288, 64, Cn);
    gemm64_kernel<<<g64, 256, 0, stream>>>(B4, Cn, a1, 64, hid + 64, 288, 64, Cn);
    gemm64_kernel<<<g64, 256, 0, stream>>>(B3, Cn, v1, 32, hid + 128, 288, 32, Cn);
    gemm64_kernel<<<dim3(64, 2), 256, 0, stream>>>(B5, Cn, g1w, 128, hid + 160, 288, 128, Cn);
    hidact_kernel<<<4608, 256, 0, stream>>>(hid);
    // stage 3: lora-up GEMMs
    gemm64_kernel<<<gBig, 256, 0, stream>>>(hid + 0, 288, w2, Cn, B0, Cn, Cn, 64);
    gemm64_kernel<<<gBig, 256, 0, stream>>>(hid + 64, 288, a2, Cn, B2, Cn, Cn, 64);
    gemm64_kernel<<<gBig, 256, 0, stream>>>(hid + 128, 288, v2, Cn, B3, Cn, Cn, 32);
    gemm64_kernel<<<gBig, 256, 0, stream>>>(hid + 160, 288, g2w, Cn, B5, Cn, Cn, 128);
    // stage 3e: elementwise + head-norm
    stage3e_kernel<<<15360, 256, 0, stream>>>(B0, B2, B3, B7, v_first,
                                              w0, a0, v0c, k_k, k_a,
                                              B1, B8, B0, B2, B3);
    // stage 4: sequential scan + groupnorm + bonus + gate
    scan_kernel<<<60, 256, 0, stream>>>(B6, B1, B3, B0, B2, B8, B5,
                                        r_k, ln_g, ln_b, B4);
    // stage 5: output projection
    gemm64_kernel<<<gBig, 256, 0, stream>>>(B4, Cn, Wo, Cn, out, Cn, Cn, Cn);
}

// Round 2
// 1398.470 us; speedup vs baseline: 1.3262x; 1.3262x over previous
//
#include <hip/hip_runtime.h>
#include <hip/hip_bf16.h>
#include <math.h>

#define Tn 1024
#define Cn 960
#define Hn 15
#define Nn 64
#define Mn 4096  // B*T

__device__ __forceinline__ float sigmf(float x) { return 1.0f / (1.0f + __expf(-x)); }

// ---------------------------------------------------------------------------
// token-shift + 6 mixes: out_j = x + (shift(x) - x) * mix_j
// ---------------------------------------------------------------------------
__global__ __launch_bounds__(256) void mix6_kernel(
    const float* __restrict__ x,
    const float* __restrict__ mr, const float* __restrict__ mw, const float* __restrict__ mk,
    const float* __restrict__ mv, const float* __restrict__ ma, const float* __restrict__ mg,
    float* __restrict__ o_r, float* __restrict__ o_w, float* __restrict__ o_k,
    float* __restrict__ o_v, float* __restrict__ o_a, float* __restrict__ o_g)
{
    int idx = blockIdx.x * 256 + threadIdx.x;  // float4 index
    int e = idx * 4;
    if (e >= Mn * Cn) return;
    int m = e / Cn;
    int c = e - m * Cn;
    int t = m & (Tn - 1);
    float4 xv = *(const float4*)(x + e);
    float4 xp = make_float4(0.f, 0.f, 0.f, 0.f);
    if (t > 0) xp = *(const float4*)(x + e - Cn);
    float4 dx = make_float4(xp.x - xv.x, xp.y - xv.y, xp.z - xv.z, xp.w - xv.w);
#define APPLY(MIXP, OUTP)                                                     \
    {                                                                         \
        float4 mm = *(const float4*)(MIXP + c);                               \
        float4 o = make_float4(xv.x + dx.x * mm.x, xv.y + dx.y * mm.y,        \
                               xv.z + dx.z * mm.z, xv.w + dx.w * mm.w);       \
        *(float4*)(OUTP + e) = o;                                             \
    }
    APPLY(mr, o_r) APPLY(mw, o_w) APPLY(mk, o_k)
    APPLY(mv, o_v) APPLY(ma, o_a) APPLY(mg, o_g)
#undef APPLY
}

// ---------------------------------------------------------------------------
// plain f32 GEMM: C[M,N] = A[M,K] @ B[K,N].  M from grid (64/row-tile).
// BM=64 BN=64 BK=16, 256 threads, 4x4 per thread.
// ---------------------------------------------------------------------------
__global__ __launch_bounds__(256) void gemm64_kernel(
    const float* __restrict__ A, int lda,
    const float* __restrict__ Bw, int ldb,
    float* __restrict__ Cc, int ldc, int N, int K)
{
    __shared__ float As[16][68];
    __shared__ float Bs[16][64];
    int bm = blockIdx.x * 64, bn = blockIdx.y * 64;
    int tid = threadIdx.x;
    int tx = tid & 15, ty = tid >> 4;
    int ar = tid >> 2, ak = (tid & 3) * 4;
    int bkr = tid >> 4, bnc = (tid & 15) * 4;
    bool bok = (bn + bnc) < N;
    const float* Aptr = A + (size_t)(bm + ar) * lda + ak;
    const float* Bptr = Bw + (size_t)bkr * ldb + bn + bnc;
    float acc[4][4];
#pragma unroll
    for (int i = 0; i < 4; ++i)
#pragma unroll
        for (int j = 0; j < 4; ++j) acc[i][j] = 0.f;

    for (int k0 = 0; k0 < K; k0 += 16) {
        float4 a4 = *(const float4*)(Aptr + k0);
        float4 b4 = make_float4(0.f, 0.f, 0.f, 0.f);
        if (bok) b4 = *(const float4*)(Bptr + (size_t)k0 * ldb);
        As[ak + 0][ar] = a4.x;
        As[ak + 1][ar] = a4.y;
        As[ak + 2][ar] = a4.z;
        As[ak + 3][ar] = a4.w;
        *(float4*)&Bs[bkr][bnc] = b4;
        __syncthreads();
#pragma unroll
        for (int kk = 0; kk < 16; ++kk) {
            float4 av = *(const float4*)&As[kk][ty * 4];
            float4 bv = *(const float4*)&Bs[kk][tx * 4];
            float aa[4] = {av.x, av.y, av.z, av.w};
            float bb[4] = {bv.x, bv.y, bv.z, bv.w};
#pragma unroll
            for (int i = 0; i < 4; ++i)
#pragma unroll
                for (int j = 0; j < 4; ++j) acc[i][j] += aa[i] * bb[j];
        }
        __syncthreads();
    }
    if (bok) {
#pragma unroll
        for (int i = 0; i < 4; ++i) {
            int row = bm + ty * 4 + i;
            float4 st = make_float4(acc[i][0], acc[i][1], acc[i][2], acc[i][3]);
            *(float4*)(Cc + (size_t)row * ldc + bn + tx * 4) = st;
        }
    }
}

// ---------------------------------------------------------------------------
// activations on hid: cols [0,64) tanh (w), [160,288) sigmoid (g)
// ---------------------------------------------------------------------------
__global__ __launch_bounds__(256) void hidact_kernel(float* hid)
{
    int idx = blockIdx.x * 256 + threadIdx.x;
    if (idx >= Mn * 288) return;
    int c = idx % 288;
    float v = hid[idx];
    if (c < 64) v = tanhf(v);
    else if (c >= 160) v = sigmf(v);
    hid[idx] = v;
}

// ---------------------------------------------------------------------------
// elementwise stage 3: w, a, v-residual, kk-norm, kh, ah, bh.
// ---------------------------------------------------------------------------
__global__ __launch_bounds__(256) void stage3e_kernel(
    const float* wrawp, const float* aprep, const float* vsigp,
    const float* kraw, const float* vfirst,
    const float* w0, const float* a0, const float* v0c,
    const float* kkc, const float* kac,
    float* w_out, float* v_io, float* ah_out, float* bh_out, float* kh_out)
{
    int p = blockIdx.x * 4 + (threadIdx.x >> 6);
    int l = threadIdx.x & 63;
    int m = p / Hn;
    int h = p - m * Hn;
    int c = h * 64 + l;
    size_t idx = (size_t)m * Cn + c;
    float k = kraw[idx];
    float wr = w0[c] + wrawp[idx];
    float a = sigmf(a0[c] + aprep[idx]);
    float vs = sigmf(v0c[c] + vsigp[idx]);
    float v0g = v_io[idx];
    float v = v0g + (vfirst[idx] - v0g) * vs;
    float kk = k * kkc[c];
    float ss = kk * kk;
#pragma unroll
    for (int o = 32; o; o >>= 1) ss += __shfl_xor(ss, o);
    float inv = 1.0f / fmaxf(sqrtf(ss), 1e-12f);
    kk *= inv;
    float w = sigmf(wr) * 0.60653065971263342f;  // sigmoid(wr)*exp(-0.5)
    float kh = k * (1.0f + (a - 1.0f) * kac[c]);
    w_out[idx] = w;
    v_io[idx] = v;
    ah_out[idx] = -kk;
    bh_out[idx] = kk * a;
    kh_out[idx] = kh;
}

// ---------------------------------------------------------------------------
// barrier-free sequential WKV scan.
// grid = B*H*4 blocks of ONE wave (64 threads). Block (bh, q) owns rows
// [16q, 16q+16) of chain bh. lane = (row=l>>2, cg=l&3); lane owns state
// row, cols [16*cg, 16*cg+16). Per-step vectors staged in private LDS —
// wave-synchronous (lgkmcnt only, NO s_barrier). Raw wkv out; norm later.
// ---------------------------------------------------------------------------
__global__ __launch_bounds__(64) void scan_kernel(
    const float* __restrict__ rP, const float* __restrict__ wP,
    const float* __restrict__ kP, const float* __restrict__ aP,
    const float* __restrict__ bP, const float* __restrict__ vP,
    float* __restrict__ wkv)
{
    __shared__ float buf[6][64];  // r,w,k,a,b,v
    int l = threadIdx.x;
    int blk = blockIdx.x;
    int bh = blk >> 2, q = blk & 3;
    int bb = bh / Hn, h = bh - bb * Hn;
    size_t base = (size_t)bb * Tn * Cn + h * 64;
    int rl = l >> 2, cg = l & 3;
    int c0 = cg * 16;
    int arow = q * 16 + rl;

    const float* pr = rP + base + l;
    const float* pw = wP + base + l;
    const float* pk = kP + base + l;
    const float* pa = aP + base + l;
    const float* pb = bP + base + l;
    const float* pv = vP + base + l;

    float s[16];
#pragma unroll
    for (int z = 0; z < 16; ++z) s[z] = 0.f;

    float f0 = *pr, f1 = *pw, f2 = *pk, f3 = *pa, f4 = *pb, f5 = *pv;
    float* po = wkv + base + arow;

    for (int t = 0; t < Tn; ++t) {
        buf[0][l] = f0;
        buf[1][l] = f1;
        buf[2][l] = f2;
        buf[3][l] = f3;
        buf[4][l] = f4;
        buf[5][l] = f5;
        // prefetch t+1 (vmcnt stays in flight; lgkm wait below is DS-only)
        int adv = (t < Tn - 1) ? Cn : 0;
        pr += adv; pw += adv; pk += adv; pa += adv; pb += adv; pv += adv;
        f0 = *pr; f1 = *pw; f2 = *pk; f3 = *pa; f4 = *pb; f5 = *pv;
        asm volatile("s_waitcnt lgkmcnt(0)" ::: "memory");

        // sa partial over own 16 columns
        float sp0 = 0.f, sp1 = 0.f, sp2 = 0.f, sp3 = 0.f;
#pragma unroll
        for (int z = 0; z < 16; z += 4) {
            float4 a4 = *(const float4*)&buf[3][c0 + z];
            sp0 += s[z + 0] * a4.x;
            sp1 += s[z + 1] * a4.y;
            sp2 += s[z + 2] * a4.z;
            sp3 += s[z + 3] * a4.w;
        }
        float sa = (sp0 + sp1) + (sp2 + sp3);
        sa += __shfl_xor(sa, 1);
        sa += __shfl_xor(sa, 2);
        float vi = buf[5][arow];

        float op = 0.f;
#pragma unroll
        for (int z = 0; z < 16; z += 4) {
            float4 w4 = *(const float4*)&buf[1][c0 + z];
            float4 k4 = *(const float4*)&buf[2][c0 + z];
            float4 b4 = *(const float4*)&buf[4][c0 + z];
            float4 r4 = *(const float4*)&buf[0][c0 + z];
            s[z + 0] = s[z + 0] * w4.x + sa * b4.x + vi * k4.x; op += s[z + 0] * r4.x;
            s[z + 1] = s[z + 1] * w4.y + sa * b4.y + vi * k4.y; op += s[z + 1] * r4.y;
            s[z + 2] = s[z + 2] * w4.z + sa * b4.z + vi * k4.z; op += s[z + 2] * r4.z;
            s[z + 3] = s[z + 3] * w4.w + sa * b4.w + vi * k4.w; op += s[z + 3] * r4.w;
        }
        op += __shfl_xor(op, 1);
        op += __shfl_xor(op, 2);
        if (cg == 0) *po = op;
        po += Cn;
    }
}

// ---------------------------------------------------------------------------
// post-scan: per-head groupnorm + bonus + gate.  one wave per (m,h).
// ---------------------------------------------------------------------------
__global__ __launch_bounds__(256) void postnorm_kernel(
    const float* __restrict__ wkv, const float* __restrict__ rB,
    const float* __restrict__ kB, const float* __restrict__ vB,
    const float* __restrict__ gB, const float* __restrict__ r_k,
    const float* __restrict__ ln_g, const float* __restrict__ ln_b,
    float* __restrict__ xog)
{
    int grp = blockIdx.x * 4 + (threadIdx.x >> 6);
    int l = threadIdx.x & 63;
    int m = grp / Hn, h = grp - m * Hn;
    int c = h * 64 + l;
    size_t idx = (size_t)m * Cn + c;
    float out = wkv[idx];
    float rv = rB[idx], kv = kB[idx], vv = vB[idx];
    float m1 = out, m2 = out * out, bd = rv * kv * r_k[c];
#pragma unroll
    for (int o = 32; o; o >>= 1) {
        m1 += __shfl_xor(m1, o);
        m2 += __shfl_xor(m2, o);
        bd += __shfl_xor(bd, o);
    }
    float mean = m1 * (1.f / 64.f);
    float var = m2 * (1.f / 64.f) - mean * mean;
    float xn = (out - mean) * rsqrtf(var + 0.00064f) * ln_g[c] + ln_b[c];
    xog[idx] = (xn + bd * vv) * gB[idx];
}

// ---------------------------------------------------------------------------
extern "C" void kernel_launch(void* const* d_in, const int* in_sizes, int n_in,
                              void* d_out, int out_size, void* d_ws, size_t ws_size,
                              hipStream_t stream)
{
    const float* x       = (const float*)d_in[0];
    const float* v_first = (const float*)d_in[1];
    const float* x_r     = (const float*)d_in[2];
    const float* x_w     = (const float*)d_in[3];
    const float* x_k     = (const float*)d_in[4];
    const float* x_v     = (const float*)d_in[5];
    const float* x_a     = (const float*)d_in[6];
    const float* x_g     = (const float*)d_in[7];
    const float* w0      = (const float*)d_in[8];
    const float* w1      = (const float*)d_in[9];
    const float* w2      = (const float*)d_in[10];
    const float* a0      = (const float*)d_in[11];
    const float* a1      = (const float*)d_in[12];
    const float* a2      = (const float*)d_in[13];
    const float* v0c     = (const float*)d_in[14];
    const float* v1      = (const float*)d_in[15];
    const float* v2      = (const float*)d_in[16];
    const float* g1w     = (const float*)d_in[17];
    const float* g2w     = (const float*)d_in[18];
    const float* k_k     = (const float*)d_in[19];
    const float* k_a     = (const float*)d_in[20];
    const float* r_k     = (const float*)d_in[21];
    const float* Wr      = (const float*)d_in[22];
    const float* Wk      = (const float*)d_in[23];
    const float* Wv      = (const float*)d_in[24];
    const float* Wo      = (const float*)d_in[25];
    const float* ln_g    = (const float*)d_in[26];
    const float* ln_b    = (const float*)d_in[27];
    float* out = (float*)d_out;

    float* ws = (float*)d_ws;
    size_t MC = (size_t)Mn * Cn;
    float* B0 = ws + 0 * MC;  // xr -> wraw -> ah
    float* B1 = ws + 1 * MC;  // xw -> w    -> xog
    float* B2 = ws + 2 * MC;  // xk -> apre -> bh
    float* B3 = ws + 3 * MC;  // xv -> vsigp -> kh
    float* B4 = ws + 4 * MC;  // xa -> wkv (raw scan out)
    float* B5 = ws + 5 * MC;  // xg -> g
    float* B6 = ws + 6 * MC;  // r
    float* B7 = ws + 7 * MC;  // k (raw)
    float* B8 = ws + 8 * MC;  // v0 -> v
    float* hid = ws + 9 * MC; // [Mn,288]

    mix6_kernel<<<3840, 256, 0, stream>>>(x, x_r, x_w, x_k, x_v, x_a, x_g,
                                          B0, B1, B2, B3, B4, B5);

    dim3 gBig(64, 15);
    // stage 1: big projections
    gemm64_kernel<<<gBig, 256, 0, stream>>>(B0, Cn, Wr, Cn, B6, Cn, Cn, Cn);
    gemm64_kernel<<<gBig, 256, 0, stream>>>(B2, Cn, Wk, Cn, B7, Cn, Cn, Cn);
    gemm64_kernel<<<gBig, 256, 0, stream>>>(B3, Cn, Wv, Cn, B8, Cn, Cn, Cn);
    // stage 2: lora-down GEMMs into hid
    dim3 g64(64, 1);
    gemm64_kernel<<<g64, 256, 0, stream>>>(B1, Cn, w1, 64, hid + 0, 288, 64, Cn);
    gemm64_kernel<<<g64, 256, 0, stream>>>(B4, Cn, a1, 64, hid + 64, 288, 64, Cn);
    gemm64_kernel<<<g64, 256, 0, stream>>>(B3, Cn, v1, 32, hid + 128, 288, 32, Cn);
    gemm64_kernel<<<dim3(64, 2), 256, 0, stream>>>(B5, Cn, g1w, 128, hid + 160, 288, 128, Cn);
    hidact_kernel<<<4608, 256, 0, stream>>>(hid);
    // stage 3: lora-up GEMMs
    gemm64_kernel<<<gBig, 256, 0, stream>>>(hid + 0, 288, w2, Cn, B0, Cn, Cn, 64);
    gemm64_kernel<<<gBig, 256, 0, stream>>>(hid + 64, 288, a2, Cn, B2, Cn, Cn, 64);
    gemm64_kernel<<<gBig, 256, 0, stream>>>(hid + 128, 288, v2, Cn, B3, Cn, Cn, 32);
    gemm64_kernel<<<gBig, 256, 0, stream>>>(hid + 160, 288, g2w, Cn, B5, Cn, Cn, 128);
    // stage 3e: elementwise + head-norm
    stage3e_kernel<<<15360, 256, 0, stream>>>(B0, B2, B3, B7, v_first,
                                              w0, a0, v0c, k_k, k_a,
                                              B1, B8, B0, B2, B3);
    // stage 4: barrier-free sequential scan (raw wkv out)
    scan_kernel<<<240, 64, 0, stream>>>(B6, B1, B3, B0, B2, B8, B4);
    // stage 4b: groupnorm + bonus + gate
    postnorm_kernel<<<15360, 256, 0, stream>>>(B4, B6, B3, B8, B5,
                                               r_k, ln_g, ln_b, B1);
    // stage 5: output projection
    gemm64_kernel<<<gBig, 256, 0, stream>>>(B1, Cn, Wo, Cn, out, Cn, Cn, Cn);
}

// Round 3
// 1302.759 us; speedup vs baseline: 1.4236x; 1.0735x over previous
//
#include <hip/hip_runtime.h>
#include <hip/hip_bf16.h>
#include <math.h>

#define Tn 1024
#define Cn 960
#define Hn 15
#define Nn 64
#define Mn 4096  // B*T

__device__ __forceinline__ float sigmf(float x) { return 1.0f / (1.0f + __expf(-x)); }

// ---------------------------------------------------------------------------
// token-shift + 6 mixes: out_j = x + (shift(x) - x) * mix_j
// ---------------------------------------------------------------------------
__global__ __launch_bounds__(256) void mix6_kernel(
    const float* __restrict__ x,
    const float* __restrict__ mr, const float* __restrict__ mw, const float* __restrict__ mk,
    const float* __restrict__ mv, const float* __restrict__ ma, const float* __restrict__ mg,
    float* __restrict__ o_r, float* __restrict__ o_w, float* __restrict__ o_k,
    float* __restrict__ o_v, float* __restrict__ o_a, float* __restrict__ o_g)
{
    int idx = blockIdx.x * 256 + threadIdx.x;  // float4 index
    int e = idx * 4;
    if (e >= Mn * Cn) return;
    int m = e / Cn;
    int c = e - m * Cn;
    int t = m & (Tn - 1);
    float4 xv = *(const float4*)(x + e);
    float4 xp = make_float4(0.f, 0.f, 0.f, 0.f);
    if (t > 0) xp = *(const float4*)(x + e - Cn);
    float4 dx = make_float4(xp.x - xv.x, xp.y - xv.y, xp.z - xv.z, xp.w - xv.w);
#define APPLY(MIXP, OUTP)                                                     \
    {                                                                         \
        float4 mm = *(const float4*)(MIXP + c);                               \
        float4 o = make_float4(xv.x + dx.x * mm.x, xv.y + dx.y * mm.y,        \
                               xv.z + dx.z * mm.z, xv.w + dx.w * mm.w);       \
        *(float4*)(OUTP + e) = o;                                             \
    }
    APPLY(mr, o_r) APPLY(mw, o_w) APPLY(mk, o_k)
    APPLY(mv, o_v) APPLY(ma, o_a) APPLY(mg, o_g)
#undef APPLY
}

// ---------------------------------------------------------------------------
// plain f32 GEMM: C[M,N] = A[M,K] @ B[K,N].  M from grid (64/row-tile).
// BM=64 BN=64 BK=16, 256 threads, 4x4 per thread.
// ---------------------------------------------------------------------------
__global__ __launch_bounds__(256) void gemm64_kernel(
    const float* __restrict__ A, int lda,
    const float* __restrict__ Bw, int ldb,
    float* __restrict__ Cc, int ldc, int N, int K)
{
    __shared__ float As[16][68];
    __shared__ float Bs[16][64];
    int bm = blockIdx.x * 64, bn = blockIdx.y * 64;
    int tid = threadIdx.x;
    int tx = tid & 15, ty = tid >> 4;
    int ar = tid >> 2, ak = (tid & 3) * 4;
    int bkr = tid >> 4, bnc = (tid & 15) * 4;
    bool bok = (bn + bnc) < N;
    const float* Aptr = A + (size_t)(bm + ar) * lda + ak;
    const float* Bptr = Bw + (size_t)bkr * ldb + bn + bnc;
    float acc[4][4];
#pragma unroll
    for (int i = 0; i < 4; ++i)
#pragma unroll
        for (int j = 0; j < 4; ++j) acc[i][j] = 0.f;

    for (int k0 = 0; k0 < K; k0 += 16) {
        float4 a4 = *(const float4*)(Aptr + k0);
        float4 b4 = make_float4(0.f, 0.f, 0.f, 0.f);
        if (bok) b4 = *(const float4*)(Bptr + (size_t)k0 * ldb);
        As[ak + 0][ar] = a4.x;
        As[ak + 1][ar] = a4.y;
        As[ak + 2][ar] = a4.z;
        As[ak + 3][ar] = a4.w;
        *(float4*)&Bs[bkr][bnc] = b4;
        __syncthreads();
#pragma unroll
        for (int kk = 0; kk < 16; ++kk) {
            float4 av = *(const float4*)&As[kk][ty * 4];
            float4 bv = *(const float4*)&Bs[kk][tx * 4];
            float aa[4] = {av.x, av.y, av.z, av.w};
            float bb[4] = {bv.x, bv.y, bv.z, bv.w};
#pragma unroll
            for (int i = 0; i < 4; ++i)
#pragma unroll
                for (int j = 0; j < 4; ++j) acc[i][j] += aa[i] * bb[j];
        }
        __syncthreads();
    }
    if (bok) {
#pragma unroll
        for (int i = 0; i < 4; ++i) {
            int row = bm + ty * 4 + i;
            float4 st = make_float4(acc[i][0], acc[i][1], acc[i][2], acc[i][3]);
            *(float4*)(Cc + (size_t)row * ldc + bn + tx * 4) = st;
        }
    }
}

// ---------------------------------------------------------------------------
// activations on hid: cols [0,64) tanh (w), [160,288) sigmoid (g)
// ---------------------------------------------------------------------------
__global__ __launch_bounds__(256) void hidact_kernel(float* hid)
{
    int idx = blockIdx.x * 256 + threadIdx.x;
    if (idx >= Mn * 288) return;
    int c = idx % 288;
    float v = hid[idx];
    if (c < 64) v = tanhf(v);
    else if (c >= 160) v = sigmf(v);
    hid[idx] = v;
}

// ---------------------------------------------------------------------------
// elementwise stage 3: w, a, v-residual, kk-norm, kh, ah, bh.
// ---------------------------------------------------------------------------
__global__ __launch_bounds__(256) void stage3e_kernel(
    const float* wrawp, const float* aprep, const float* vsigp,
    const float* kraw, const float* vfirst,
    const float* w0, const float* a0, const float* v0c,
    const float* kkc, const float* kac,
    float* w_out, float* v_io, float* ah_out, float* bh_out, float* kh_out)
{
    int p = blockIdx.x * 4 + (threadIdx.x >> 6);
    int l = threadIdx.x & 63;
    int m = p / Hn;
    int h = p - m * Hn;
    int c = h * 64 + l;
    size_t idx = (size_t)m * Cn + c;
    float k = kraw[idx];
    float wr = w0[c] + wrawp[idx];
    float a = sigmf(a0[c] + aprep[idx]);
    float vs = sigmf(v0c[c] + vsigp[idx]);
    float v0g = v_io[idx];
    float v = v0g + (vfirst[idx] - v0g) * vs;
    float kk = k * kkc[c];
    float ss = kk * kk;
#pragma unroll
    for (int o = 32; o; o >>= 1) ss += __shfl_xor(ss, o);
    float inv = 1.0f / fmaxf(sqrtf(ss), 1e-12f);
    kk *= inv;
    float w = sigmf(wr) * 0.60653065971263342f;  // sigmoid(wr)*exp(-0.5)
    float kh = k * (1.0f + (a - 1.0f) * kac[c]);
    w_out[idx] = w;
    v_io[idx] = v;
    ah_out[idx] = -kk;
    bh_out[idx] = kk * a;
    kh_out[idx] = kh;
}

// ---------------------------------------------------------------------------
// barrier-free sequential WKV scan, depth-2 software pipeline.
// grid = B*H*4 blocks of ONE wave. Block (bh,q) owns rows [16q,16q+16).
// lane = (row=l>>2, cg=l&3) owns 16 state cols of one row. Per-step vectors
// staged in private double-buffered LDS; loads for step t+2 issued at step t
// so the compiler emits counted vmcnt (depth-2 latency cover). No s_barrier.
// ---------------------------------------------------------------------------
__global__ __launch_bounds__(64) void scan_kernel(
    const float* __restrict__ rP, const float* __restrict__ wP,
    const float* __restrict__ kP, const float* __restrict__ aP,
    const float* __restrict__ bP, const float* __restrict__ vP,
    float* __restrict__ wkv)
{
    __shared__ float buf[2][6][64];  // [half][r,w,k,a,b,v][64]
    int l = threadIdx.x;
    int blk = blockIdx.x;
    int bh = blk >> 2, q = blk & 3;
    int bb = bh / Hn, h = bh - bb * Hn;
    size_t base = (size_t)bb * Tn * Cn + h * 64;
    int rl = l >> 2, cg = l & 3;
    int c0 = cg * 16;
    int arow = q * 16 + rl;

    const float* pr = rP + base + l;
    const float* pw = wP + base + l;
    const float* pk = kP + base + l;
    const float* pa = aP + base + l;
    const float* pb = bP + base + l;
    const float* pv = vP + base + l;

    float s[16];
#pragma unroll
    for (int z = 0; z < 16; ++z) s[z] = 0.f;

    // preload: step 0 -> A, step 1 -> B; pointers end up at step 2
    float A0 = *pr, A1 = *pw, A2 = *pk, A3 = *pa, A4 = *pb, A5 = *pv;
    pr += Cn; pw += Cn; pk += Cn; pa += Cn; pb += Cn; pv += Cn;
    float B0 = *pr, B1 = *pw, B2 = *pk, B3 = *pa, B4 = *pb, B5 = *pv;
    pr += Cn; pw += Cn; pk += Cn; pa += Cn; pb += Cn; pv += Cn;

    float* po = wkv + base + arow;

#define STEPCOMPUTE(H)                                                        \
    {                                                                         \
        float sp0 = 0.f, sp1 = 0.f, sp2 = 0.f, sp3 = 0.f;                     \
        _Pragma("unroll")                                                     \
        for (int z = 0; z < 16; z += 4) {                                     \
            float4 a4 = *(const float4*)&buf[H][3][c0 + z];                   \
            sp0 += s[z + 0] * a4.x; sp1 += s[z + 1] * a4.y;                   \
            sp2 += s[z + 2] * a4.z; sp3 += s[z + 3] * a4.w;                   \
        }                                                                     \
        float sa = (sp0 + sp1) + (sp2 + sp3);                                 \
        sa += __shfl_xor(sa, 1);                                              \
        sa += __shfl_xor(sa, 2);                                              \
        float vi = buf[H][5][arow];                                           \
        float op0 = 0.f, op1 = 0.f, op2 = 0.f, op3 = 0.f;                     \
        _Pragma("unroll")                                                     \
        for (int z = 0; z < 16; z += 4) {                                     \
            float4 w4 = *(const float4*)&buf[H][1][c0 + z];                   \
            float4 k4 = *(const float4*)&buf[H][2][c0 + z];                   \
            float4 b4 = *(const float4*)&buf[H][4][c0 + z];                   \
            float4 r4 = *(const float4*)&buf[H][0][c0 + z];                   \
            s[z + 0] = s[z + 0] * w4.x + sa * b4.x + vi * k4.x; op0 += s[z + 0] * r4.x; \
            s[z + 1] = s[z + 1] * w4.y + sa * b4.y + vi * k4.y; op1 += s[z + 1] * r4.y; \
            s[z + 2] = s[z + 2] * w4.z + sa * b4.z + vi * k4.z; op2 += s[z + 2] * r4.z; \
            s[z + 3] = s[z + 3] * w4.w + sa * b4.w + vi * k4.w; op3 += s[z + 3] * r4.w; \
        }                                                                     \
        float op = (op0 + op1) + (op2 + op3);                                 \
        op += __shfl_xor(op, 1);                                              \
        op += __shfl_xor(op, 2);                                              \
        if (cg == 0) *po = op;                                                \
        po += Cn;                                                             \
    }

    for (int t = 0; t < Tn; t += 2) {
        // ---- half 0: step t (regs A; the vmcnt wait here is counted, A's
        //      loads were issued 2 steps ago; B's 6 loads stay outstanding)
        buf[0][0][l] = A0; buf[0][1][l] = A1; buf[0][2][l] = A2;
        buf[0][3][l] = A3; buf[0][4][l] = A4; buf[0][5][l] = A5;
        A0 = *pr; A1 = *pw; A2 = *pk; A3 = *pa; A4 = *pb; A5 = *pv;  // step t+2
        {
            int adv = (t + 3 < Tn) ? Cn : 0;
            pr += adv; pw += adv; pk += adv; pa += adv; pb += adv; pv += adv;
        }
        asm volatile("s_waitcnt lgkmcnt(0)" ::: "memory");
        STEPCOMPUTE(0)

        // ---- half 1: step t+1 (regs B)
        buf[1][0][l] = B0; buf[1][1][l] = B1; buf[1][2][l] = B2;
        buf[1][3][l] = B3; buf[1][4][l] = B4; buf[1][5][l] = B5;
        B0 = *pr; B1 = *pw; B2 = *pk; B3 = *pa; B4 = *pb; B5 = *pv;  // step t+3
        {
            int adv = (t + 4 < Tn) ? Cn : 0;
            pr += adv; pw += adv; pk += adv; pa += adv; pb += adv; pv += adv;
        }
        asm volatile("s_waitcnt lgkmcnt(0)" ::: "memory");
        STEPCOMPUTE(1)
    }
#undef STEPCOMPUTE
}

// ---------------------------------------------------------------------------
// post-scan: per-head groupnorm + bonus + gate.  one wave per (m,h).
// ---------------------------------------------------------------------------
__global__ __launch_bounds__(256) void postnorm_kernel(
    const float* __restrict__ wkv, const float* __restrict__ rB,
    const float* __restrict__ kB, const float* __restrict__ vB,
    const float* __restrict__ gB, const float* __restrict__ r_k,
    const float* __restrict__ ln_g, const float* __restrict__ ln_b,
    float* __restrict__ xog)
{
    int grp = blockIdx.x * 4 + (threadIdx.x >> 6);
    int l = threadIdx.x & 63;
    int m = grp / Hn, h = grp - m * Hn;
    int c = h * 64 + l;
    size_t idx = (size_t)m * Cn + c;
    float out = wkv[idx];
    float rv = rB[idx], kv = kB[idx], vv = vB[idx];
    float m1 = out, m2 = out * out, bd = rv * kv * r_k[c];
#pragma unroll
    for (int o = 32; o; o >>= 1) {
        m1 += __shfl_xor(m1, o);
        m2 += __shfl_xor(m2, o);
        bd += __shfl_xor(bd, o);
    }
    float mean = m1 * (1.f / 64.f);
    float var = m2 * (1.f / 64.f) - mean * mean;
    float xn = (out - mean) * rsqrtf(var + 0.00064f) * ln_g[c] + ln_b[c];
    xog[idx] = (xn + bd * vv) * gB[idx];
}

// ---------------------------------------------------------------------------
extern "C" void kernel_launch(void* const* d_in, const int* in_sizes, int n_in,
                              void* d_out, int out_size, void* d_ws, size_t ws_size,
                              hipStream_t stream)
{
    const float* x       = (const float*)d_in[0];
    const float* v_first = (const float*)d_in[1];
    const float* x_r     = (const float*)d_in[2];
    const float* x_w     = (const float*)d_in[3];
    const float* x_k     = (const float*)d_in[4];
    const float* x_v     = (const float*)d_in[5];
    const float* x_a     = (const float*)d_in[6];
    const float* x_g     = (const float*)d_in[7];
    const float* w0      = (const float*)d_in[8];
    const float* w1      = (const float*)d_in[9];
    const float* w2      = (const float*)d_in[10];
    const float* a0      = (const float*)d_in[11];
    const float* a1      = (const float*)d_in[12];
    const float* a2      = (const float*)d_in[13];
    const float* v0c     = (const float*)d_in[14];
    const float* v1      = (const float*)d_in[15];
    const float* v2      = (const float*)d_in[16];
    const float* g1w     = (const float*)d_in[17];
    const float* g2w     = (const float*)d_in[18];
    const float* k_k     = (const float*)d_in[19];
    const float* k_a     = (const float*)d_in[20];
    const float* r_k     = (const float*)d_in[21];
    const float* Wr      = (const float*)d_in[22];
    const float* Wk      = (const float*)d_in[23];
    const float* Wv      = (const float*)d_in[24];
    const float* Wo      = (const float*)d_in[25];
    const float* ln_g    = (const float*)d_in[26];
    const float* ln_b    = (const float*)d_in[27];
    float* out = (float*)d_out;

    float* ws = (float*)d_ws;
    size_t MC = (size_t)Mn * Cn;
    float* B0 = ws + 0 * MC;  // xr -> wraw -> ah
    float* B1 = ws + 1 * MC;  // xw -> w    -> xog
    float* B2 = ws + 2 * MC;  // xk -> apre -> bh
    float* B3 = ws + 3 * MC;  // xv -> vsigp -> kh
    float* B4 = ws + 4 * MC;  // xa -> wkv (raw scan out)
    float* B5 = ws + 5 * MC;  // xg -> g
    float* B6 = ws + 6 * MC;  // r
    float* B7 = ws + 7 * MC;  // k (raw)
    float* B8 = ws + 8 * MC;  // v0 -> v
    float* hid = ws + 9 * MC; // [Mn,288]

    mix6_kernel<<<3840, 256, 0, stream>>>(x, x_r, x_w, x_k, x_v, x_a, x_g,
                                          B0, B1, B2, B3, B4, B5);

    dim3 gBig(64, 15);
    // stage 1: big projections
    gemm64_kernel<<<gBig, 256, 0, stream>>>(B0, Cn, Wr, Cn, B6, Cn, Cn, Cn);
    gemm64_kernel<<<gBig, 256, 0, stream>>>(B2, Cn, Wk, Cn, B7, Cn, Cn, Cn);
    gemm64_kernel<<<gBig, 256, 0, stream>>>(B3, Cn, Wv, Cn, B8, Cn, Cn, Cn);
    // stage 2: lora-down GEMMs into hid
    dim3 g64(64, 1);
    gemm64_kernel<<<g64, 256, 0, stream>>>(B1, Cn, w1, 64, hid + 0, 288, 64, Cn);
    gemm64_kernel<<<g64, 256, 0, stream>>>(B4, Cn, a1, 64, hid + 64, 288, 64, Cn);
    gemm64_kernel<<<g64, 256, 0, stream>>>(B3, Cn, v1, 32, hid + 128, 288, 32, Cn);
    gemm64_kernel<<<dim3(64, 2), 256, 0, stream>>>(B5, Cn, g1w, 128, hid + 160, 288, 128, Cn);
    hidact_kernel<<<4608, 256, 0, stream>>>(hid);
    // stage 3: lora-up GEMMs
    gemm64_kernel<<<gBig, 256, 0, stream>>>(hid + 0, 288, w2, Cn, B0, Cn, Cn, 64);
    gemm64_kernel<<<gBig, 256, 0, stream>>>(hid + 64, 288, a2, Cn, B2, Cn, Cn, 64);
    gemm64_kernel<<<gBig, 256, 0, stream>>>(hid + 128, 288, v2, Cn, B3, Cn, Cn, 32);
    gemm64_kernel<<<gBig, 256, 0, stream>>>(hid + 160, 288, g2w, Cn, B5, Cn, Cn, 128);
    // stage 3e: elementwise + head-norm
    stage3e_kernel<<<15360, 256, 0, stream>>>(B0, B2, B3, B7, v_first,
                                              w0, a0, v0c, k_k, k_a,
                                              B1, B8, B0, B2, B3);
    // stage 4: barrier-free depth-2 pipelined scan (raw wkv out)
    scan_kernel<<<240, 64, 0, stream>>>(B6, B1, B3, B0, B2, B8, B4);
    // stage 4b: groupnorm + bonus + gate
    postnorm_kernel<<<15360, 256, 0, stream>>>(B4, B6, B3, B8, B5,
                                               r_k, ln_g, ln_b, B1);
    // stage 5: output projection
    gemm64_kernel<<<gBig, 256, 0, stream>>>(B1, Cn, Wo, Cn, out, Cn, Cn, Cn);
}